// Round 12
// baseline (190.325 us; speedup 1.0000x reference)
//
#include <hip/hip_runtime.h>

#define NPIX 15000
#define IMG_H 200
#define IMG_W 75
#define NVEC 3750   // NPIX / 4

typedef float f4 __attribute__((ext_vector_type(4)));

// Pre-kernel: wp[p] = lane_W[(p%200)*75 + p/200]  (the reshape/transpose permutation)
__global__ void eb_permute_w(const float* __restrict__ lane_W, float* __restrict__ wp) {
    int p = blockIdx.x * blockDim.x + threadIdx.x;
    if (p < NPIX) {
        int w = p / IMG_H;          // 0..74
        int h = p - w * IMG_H;      // 0..199
        wp[p] = lane_W[h * IMG_W + w];
    }
}

__device__ __forceinline__ float sel4(f4 v, f4 w) {
    float s;
    s  = (v.x > 0.0f ? w.x : 0.0f);
    s += (v.y > 0.0f ? w.y : 0.0f);
    s += (v.z > 0.0f ? w.z : 0.0f);
    s += (v.w > 0.0f ? w.w : 0.0f);
    return s;
}

// Phase 1: steer[b] = sum_p (rgb[b,p] > 0 ? wp[p] : 0) + lane_b
// Block-per-row, deep-ILP VGPR staging (R7 structure = measured best).
// SINGLE CHANGE vs R7: plain loads instead of nontemporal -> rgb lines may
// allocate in L2/L3, recovering the ~50% Infinity-Cache hit rate R1 measured
// (FETCH_SIZE 241MB of 492MB). Lower avg latency at fixed in-flight bytes.
__global__ __launch_bounds__(256, 6) void eb_reduce(
    const float* __restrict__ rgb,       // [B, 15000]
    const float* __restrict__ wp,        // [15000] permuted lane weights
    const float* __restrict__ lane_b,    // [1]
    float* __restrict__ steer)           // [B]
{
    const int b = blockIdx.x;
    const int t = threadIdx.x;

    const f4* __restrict__ row = reinterpret_cast<const f4*>(rgb + (size_t)b * NPIX);
    const f4* __restrict__ wv4 = reinterpret_cast<const f4*>(wp);

    // per-thread f4 indices: t + 256k, k=0..13 uniform; k=14 iff t < 166.
    float acc = 0.0f;
    {
        // group A: k = 0..7  (8 independent 16B loads back-to-back)
        f4 v0 = row[t];
        f4 v1 = row[t +  256];
        f4 v2 = row[t +  512];
        f4 v3 = row[t +  768];
        f4 v4 = row[t + 1024];
        f4 v5 = row[t + 1280];
        f4 v6 = row[t + 1536];
        f4 v7 = row[t + 1792];
        f4 w0 = wv4[t];
        f4 w1 = wv4[t +  256];
        f4 w2 = wv4[t +  512];
        f4 w3 = wv4[t +  768];
        f4 w4 = wv4[t + 1024];
        f4 w5 = wv4[t + 1280];
        f4 w6 = wv4[t + 1536];
        f4 w7 = wv4[t + 1792];
        acc += sel4(v0, w0); acc += sel4(v1, w1);
        acc += sel4(v2, w2); acc += sel4(v3, w3);
        acc += sel4(v4, w4); acc += sel4(v5, w5);
        acc += sel4(v6, w6); acc += sel4(v7, w7);
    }
    {
        // group B: k = 8..13
        f4 v0 = row[t + 2048];
        f4 v1 = row[t + 2304];
        f4 v2 = row[t + 2560];
        f4 v3 = row[t + 2816];
        f4 v4 = row[t + 3072];
        f4 v5 = row[t + 3328];
        f4 w0 = wv4[t + 2048];
        f4 w1 = wv4[t + 2304];
        f4 w2 = wv4[t + 2560];
        f4 w3 = wv4[t + 2816];
        f4 w4 = wv4[t + 3072];
        f4 w5 = wv4[t + 3328];
        acc += sel4(v0, w0); acc += sel4(v1, w1);
        acc += sel4(v2, w2); acc += sel4(v3, w3);
        acc += sel4(v4, w4); acc += sel4(v5, w5);
    }
    // tail: k = 14, f4 index 3584 + t, valid for t < 166
    if (t < NVEC - 3584) {
        f4 v = row[t + 3584];
        f4 w = wv4[t + 3584];
        acc += sel4(v, w);
    }

    // wave64 butterfly reduce, then cross-wave via LDS
    #pragma unroll
    for (int off = 32; off > 0; off >>= 1)
        acc += __shfl_down(acc, off, 64);

    __shared__ float partial[4];
    const int wave = t >> 6;
    if ((t & 63) == 0) partial[wave] = acc;
    __syncthreads();

    if (t == 0)
        steer[b] = ((partial[0] + partial[1]) + (partial[2] + partial[3])) + lane_b[0];
}

// Phase 2: one thread per batch element runs the whole dueling MLP.
__global__ __launch_bounds__(256) void eb_mlp(
    const float* __restrict__ steer,     // [B]
    const float* __restrict__ distance,  // [B]
    const float* __restrict__ kmph,      // [B]
    const float* __restrict__ W1, const float* __restrict__ b1,   // [3,16],[16]
    const float* __restrict__ W2, const float* __restrict__ b2,   // [16,32],[32]
    const float* __restrict__ W3, const float* __restrict__ b3,   // [32,32],[32]
    const float* __restrict__ W4, const float* __restrict__ b4,   // [32,16],[16]
    const float* __restrict__ Wv, const float* __restrict__ bv,   // [16,1],[1]
    const float* __restrict__ Wa, const float* __restrict__ ba,   // [16,4],[4]
    float* __restrict__ out,             // [B, 4]
    int B)
{
    const int b = blockIdx.x * blockDim.x + threadIdx.x;
    if (b >= B) return;

    const float fc0 = steer[b];
    const float fc1 = distance[b];
    const float fc2 = kmph[b];

    float h1[16];
    #pragma unroll
    for (int j = 0; j < 16; ++j) {
        float s = b1[j];
        s += fc0 * W1[0 * 16 + j];
        s += fc1 * W1[1 * 16 + j];
        s += fc2 * W1[2 * 16 + j];
        h1[j] = s > 0.0f ? s : 0.0f;
    }
    float h2[32];
    #pragma unroll
    for (int j = 0; j < 32; ++j) {
        float s = b2[j];
        #pragma unroll
        for (int i = 0; i < 16; ++i) s += h1[i] * W2[i * 32 + j];
        h2[j] = s > 0.0f ? s : 0.0f;
    }
    float h3[32];
    #pragma unroll
    for (int j = 0; j < 32; ++j) {
        float s = b3[j];
        #pragma unroll
        for (int i = 0; i < 32; ++i) s += h2[i] * W3[i * 32 + j];
        h3[j] = s > 0.0f ? s : 0.0f;
    }
    float h4[16];
    #pragma unroll
    for (int j = 0; j < 16; ++j) {
        float s = b4[j];
        #pragma unroll
        for (int i = 0; i < 32; ++i) s += h3[i] * W4[i * 16 + j];
        h4[j] = s;
    }
    float value = bv[0];
    #pragma unroll
    for (int i = 0; i < 16; ++i) value += h4[i] * Wv[i];
    float a0 = ba[0], a1 = ba[1], a2 = ba[2], a3 = ba[3];
    #pragma unroll
    for (int i = 0; i < 16; ++i) {
        a0 += h4[i] * Wa[i * 4 + 0];
        a1 += h4[i] * Wa[i * 4 + 1];
        a2 += h4[i] * Wa[i * 4 + 2];
        a3 += h4[i] * Wa[i * 4 + 3];
    }
    float mean = (((a0 + a1) + a2) + a3) * 0.25f;

    float4 o;
    o.x = value + (a0 - mean);
    o.y = value + (a1 - mean);
    o.z = value + (a2 - mean);
    o.w = value + (a3 - mean);
    reinterpret_cast<float4*>(out)[b] = o;
}

extern "C" void kernel_launch(void* const* d_in, const int* in_sizes, int n_in,
                              void* d_out, int out_size, void* d_ws, size_t ws_size,
                              hipStream_t stream) {
    const float* rgb      = (const float*)d_in[0];
    const float* distance = (const float*)d_in[1];
    const float* kmph     = (const float*)d_in[2];
    const float* lane_W   = (const float*)d_in[3];
    const float* lane_b   = (const float*)d_in[4];
    const float* W1 = (const float*)d_in[5];
    const float* b1 = (const float*)d_in[6];
    const float* W2 = (const float*)d_in[7];
    const float* b2 = (const float*)d_in[8];
    const float* W3 = (const float*)d_in[9];
    const float* b3 = (const float*)d_in[10];
    const float* W4 = (const float*)d_in[11];
    const float* b4 = (const float*)d_in[12];
    const float* Wv = (const float*)d_in[13];
    const float* bv = (const float*)d_in[14];
    const float* Wa = (const float*)d_in[15];
    const float* ba = (const float*)d_in[16];

    const int B = in_sizes[1];          // distance has B elements

    float* wp    = (float*)d_ws;                 // 15000 floats = 60 KB
    float* steer = (float*)d_ws + 15104;         // [B] floats

    eb_permute_w<<<(NPIX + 255) / 256, 256, 0, stream>>>(lane_W, wp);
    eb_reduce<<<B, 256, 0, stream>>>(rgb, wp, lane_b, steer);
    eb_mlp<<<(B + 255) / 256, 256, 0, stream>>>(steer, distance, kmph,
                                                W1, b1, W2, b2, W3, b3, W4, b4,
                                                Wv, bv, Wa, ba, (float*)d_out, B);
}

// Round 13
// 140.589 us; speedup vs baseline: 1.3538x; 1.3538x over previous
//
#include <hip/hip_runtime.h>

#define NPIX 15000
#define IMG_H 200
#define IMG_W 75
#define NVEC 3750     // NPIX / 4
#define RPB 8         // rows per block
#define TAIL_T 166    // g=14 group: f4 index 3584+t valid for t<166

typedef float f4 __attribute__((ext_vector_type(4)));

// Pre-kernel: wp[p] = lane_W[(p%200)*75 + p/200]  (the reshape/transpose permutation)
__global__ void eb_permute_w(const float* __restrict__ lane_W, float* __restrict__ wp) {
    int p = blockIdx.x * blockDim.x + threadIdx.x;
    if (p < NPIX) {
        int w = p / IMG_H;          // 0..74
        int h = p - w * IMG_H;      // 0..199
        wp[p] = lane_W[h * IMG_W + w];
    }
}

__device__ __forceinline__ float sel4(f4 v, f4 w) {
    float s;
    s  = (v.x > 0.0f ? w.x : 0.0f);
    s += (v.y > 0.0f ? w.y : 0.0f);
    s += (v.z > 0.0f ? w.z : 0.0f);
    s += (v.w > 0.0f ? w.w : 0.0f);
    return s;
}

// Phase 1: steer[b] = sum_p (rgb[b,p] > 0 ? wp[p] : 0) + lane_b
// 8 rows per block; wp f4 loaded ONCE per column-group into registers and
// reused across the 8 rows -> total delivered bytes drop from 984 MB
// (rgb+wp per-row) to ~553 MB. R7 measured 6.9 TB/s aggregate = ceiling,
// so traffic, not latency, is the lever.
__global__ __launch_bounds__(256, 4) void eb_reduce(
    const float* __restrict__ rgb,       // [B, 15000]
    const float* __restrict__ wp,        // [15000] permuted lane weights
    const float* __restrict__ lane_b,    // [1]
    float* __restrict__ steer)           // [B]
{
    const int t = threadIdx.x;
    const int wave = t >> 6;
    const int lane = t & 63;

    const float* gw = rgb + (size_t)blockIdx.x * RPB * NPIX;
    const f4* __restrict__ wv4 = reinterpret_cast<const f4*>(wp);

    float acc[RPB];
    #pragma unroll
    for (int r = 0; r < RPB; ++r) acc[r] = 0.0f;

    // full column-groups g = 0..13 (f4 index g*256 + t)
    #pragma unroll 1
    for (int g = 0; g < 14; ++g) {
        const int idx = (g << 8) + t;          // f4 index into the row
        const f4 w = wv4[idx];
        f4 v[RPB];
        #pragma unroll
        for (int r = 0; r < RPB; ++r)
            v[r] = __builtin_nontemporal_load(
                reinterpret_cast<const f4*>(gw + (size_t)r * NPIX) + idx);
        #pragma unroll
        for (int r = 0; r < RPB; ++r)
            acc[r] += sel4(v[r], w);
    }
    // tail group g = 14: f4 index 3584 + t, valid for t < 166
    if (t < TAIL_T) {
        const int idx = 3584 + t;
        const f4 w = wv4[idx];
        f4 v[RPB];
        #pragma unroll
        for (int r = 0; r < RPB; ++r)
            v[r] = __builtin_nontemporal_load(
                reinterpret_cast<const f4*>(gw + (size_t)r * NPIX) + idx);
        #pragma unroll
        for (int r = 0; r < RPB; ++r)
            acc[r] += sel4(v[r], w);
    }

    // per-row reduction: wave64 butterfly, then cross-wave via LDS
    __shared__ float part[RPB][4];
    #pragma unroll
    for (int r = 0; r < RPB; ++r) {
        float a = acc[r];
        #pragma unroll
        for (int off = 32; off > 0; off >>= 1)
            a += __shfl_down(a, off, 64);
        if (lane == 0) part[r][wave] = a;
    }
    __syncthreads();

    if (t < RPB)
        steer[blockIdx.x * RPB + t] =
            ((part[t][0] + part[t][1]) + (part[t][2] + part[t][3])) + lane_b[0];
}

// Phase 2: one thread per batch element runs the whole dueling MLP.
__global__ __launch_bounds__(256) void eb_mlp(
    const float* __restrict__ steer,     // [B]
    const float* __restrict__ distance,  // [B]
    const float* __restrict__ kmph,      // [B]
    const float* __restrict__ W1, const float* __restrict__ b1,   // [3,16],[16]
    const float* __restrict__ W2, const float* __restrict__ b2,   // [16,32],[32]
    const float* __restrict__ W3, const float* __restrict__ b3,   // [32,32],[32]
    const float* __restrict__ W4, const float* __restrict__ b4,   // [32,16],[16]
    const float* __restrict__ Wv, const float* __restrict__ bv,   // [16,1],[1]
    const float* __restrict__ Wa, const float* __restrict__ ba,   // [16,4],[4]
    float* __restrict__ out,             // [B, 4]
    int B)
{
    const int b = blockIdx.x * blockDim.x + threadIdx.x;
    if (b >= B) return;

    const float fc0 = steer[b];
    const float fc1 = distance[b];
    const float fc2 = kmph[b];

    float h1[16];
    #pragma unroll
    for (int j = 0; j < 16; ++j) {
        float s = b1[j];
        s += fc0 * W1[0 * 16 + j];
        s += fc1 * W1[1 * 16 + j];
        s += fc2 * W1[2 * 16 + j];
        h1[j] = s > 0.0f ? s : 0.0f;
    }
    float h2[32];
    #pragma unroll
    for (int j = 0; j < 32; ++j) {
        float s = b2[j];
        #pragma unroll
        for (int i = 0; i < 16; ++i) s += h1[i] * W2[i * 32 + j];
        h2[j] = s > 0.0f ? s : 0.0f;
    }
    float h3[32];
    #pragma unroll
    for (int j = 0; j < 32; ++j) {
        float s = b3[j];
        #pragma unroll
        for (int i = 0; i < 32; ++i) s += h2[i] * W3[i * 32 + j];
        h3[j] = s > 0.0f ? s : 0.0f;
    }
    float h4[16];
    #pragma unroll
    for (int j = 0; j < 16; ++j) {
        float s = b4[j];
        #pragma unroll
        for (int i = 0; i < 32; ++i) s += h3[i] * W4[i * 16 + j];
        h4[j] = s;
    }
    float value = bv[0];
    #pragma unroll
    for (int i = 0; i < 16; ++i) value += h4[i] * Wv[i];
    float a0 = ba[0], a1 = ba[1], a2 = ba[2], a3 = ba[3];
    #pragma unroll
    for (int i = 0; i < 16; ++i) {
        a0 += h4[i] * Wa[i * 4 + 0];
        a1 += h4[i] * Wa[i * 4 + 1];
        a2 += h4[i] * Wa[i * 4 + 2];
        a3 += h4[i] * Wa[i * 4 + 3];
    }
    float mean = (((a0 + a1) + a2) + a3) * 0.25f;

    float4 o;
    o.x = value + (a0 - mean);
    o.y = value + (a1 - mean);
    o.z = value + (a2 - mean);
    o.w = value + (a3 - mean);
    reinterpret_cast<float4*>(out)[b] = o;
}

extern "C" void kernel_launch(void* const* d_in, const int* in_sizes, int n_in,
                              void* d_out, int out_size, void* d_ws, size_t ws_size,
                              hipStream_t stream) {
    const float* rgb      = (const float*)d_in[0];
    const float* distance = (const float*)d_in[1];
    const float* kmph     = (const float*)d_in[2];
    const float* lane_W   = (const float*)d_in[3];
    const float* lane_b   = (const float*)d_in[4];
    const float* W1 = (const float*)d_in[5];
    const float* b1 = (const float*)d_in[6];
    const float* W2 = (const float*)d_in[7];
    const float* b2 = (const float*)d_in[8];
    const float* W3 = (const float*)d_in[9];
    const float* b3 = (const float*)d_in[10];
    const float* W4 = (const float*)d_in[11];
    const float* b4 = (const float*)d_in[12];
    const float* Wv = (const float*)d_in[13];
    const float* bv = (const float*)d_in[14];
    const float* Wa = (const float*)d_in[15];
    const float* ba = (const float*)d_in[16];

    const int B = in_sizes[1];          // distance has B elements

    float* wp    = (float*)d_ws;                 // 15000 floats = 60 KB
    float* steer = (float*)d_ws + 15104;         // [B] floats

    eb_permute_w<<<(NPIX + 255) / 256, 256, 0, stream>>>(lane_W, wp);
    eb_reduce<<<B / RPB, 256, 0, stream>>>(rgb, wp, lane_b, steer);
    eb_mlp<<<(B + 255) / 256, 256, 0, stream>>>(steer, distance, kmph,
                                                W1, b1, W2, b2, W3, b3, W4, b4,
                                                Wv, bv, Wa, ba, (float*)d_out, B);
}